// Round 5
// baseline (328.418 us; speedup 1.0000x reference)
//
#include <hip/hip_runtime.h>
#include <stdint.h>
#include <math.h>

typedef unsigned short u16;
typedef unsigned int u32;
typedef __attribute__((ext_vector_type(8))) short bf16x8;
typedef __attribute__((ext_vector_type(4))) float f32x4;

#define SEQ 2048
#define HID 2048
#define NH  16
#define DH  128
#define NB  2

typedef __attribute__((address_space(1))) const u32 gu32;
typedef __attribute__((address_space(3))) u32 lu32;

__device__ __forceinline__ u16 f2bf(float f) {
  u32 u = __float_as_uint(f);
  return (u16)((u + 0x7fffu + ((u >> 16) & 1u)) >> 16);
}
__device__ __forceinline__ float bf2f(u16 h) { return __uint_as_float(((u32)h) << 16); }

__device__ __forceinline__ void gload_lds16(const void* g, void* l) {
  __builtin_amdgcn_global_load_lds((gu32*)g, (lu32*)l, 16, 0, 0);
}

// ---------------- fp32 -> bf16 convert ----------------
__global__ __launch_bounds__(256) void k_cvt(const float* __restrict__ src, u16* __restrict__ dst, int n4) {
  int i = blockIdx.x * 256 + threadIdx.x;
  int stride = gridDim.x * 256;
  for (; i < n4; i += stride) {
    float4 v = ((const float4*)src)[i];
    ushort4 o;
    o.x = f2bf(v.x); o.y = f2bf(v.y); o.z = f2bf(v.z); o.w = f2bf(v.w);
    ((ushort4*)dst)[i] = o;
  }
}

// ================= 256x256 8-phase GEMM (qkv projection, scatter epilogue) =================
// C = A * B^T, A:[M,K]=[4096,2048], B:[N,K]=[6144,2048] bf16, scatter to Qr/Kr/Vr.
// 512 thr = 8 waves (2M x 4N), per-wave 128x64, BK=64, 2 K-tiles/iter, 8 phases.
__device__ __forceinline__ void rd_a8(bf16x8 (&areg)[4][2], const char* sA, const int (&aoff)[4][2], int hi) {
  #pragma unroll
  for (int mm = 0; mm < 4; ++mm)
    #pragma unroll
    for (int ks = 0; ks < 2; ++ks)
      areg[mm][ks] = *(const bf16x8*)(sA + aoff[mm][ks] + hi);
}
__device__ __forceinline__ void rd_b8(bf16x8 (&breg)[4][2], const char* sB, const int (&boff)[4][2]) {
  #pragma unroll
  for (int nn = 0; nn < 4; ++nn)
    #pragma unroll
    for (int ks = 0; ks < 2; ++ks)
      breg[nn][ks] = *(const bf16x8*)(sB + boff[nn][ks]);
}
__device__ __forceinline__ void mfma_quad(f32x4 (&acc)[8][4], const bf16x8 (&areg)[4][2],
                                          const bf16x8 (&breg)[4][2], int MB, int NBq) {
  #pragma unroll
  for (int mm = 0; mm < 4; ++mm)
    #pragma unroll
    for (int nn = 0; nn < 2; ++nn)
      #pragma unroll
      for (int ks = 0; ks < 2; ++ks)
        acc[MB + mm][NBq + nn] =
            __builtin_amdgcn_mfma_f32_16x16x32_bf16(areg[mm][ks], breg[NBq + nn][ks], acc[MB + mm][NBq + nn], 0, 0, 0);
}

#define PH_PRE() do { __builtin_amdgcn_s_barrier(); \
  asm volatile("s_waitcnt lgkmcnt(0)" ::: "memory"); \
  __builtin_amdgcn_sched_barrier(0); \
  __builtin_amdgcn_s_setprio(1); } while (0)
#define PH_POST() do { __builtin_amdgcn_s_setprio(0); __builtin_amdgcn_s_barrier(); } while (0)

__global__ __launch_bounds__(512, 2)
void k_gemm8(const u16* __restrict__ A, const u16* __restrict__ Bm,
             u16* __restrict__ Qr, u16* __restrict__ Kr, u16* __restrict__ Vr, int K) {
  __shared__ alignas(16) char sA0[32768];
  __shared__ alignas(16) char sB0[32768];
  __shared__ alignas(16) char sA1[32768];
  __shared__ alignas(16) char sB1[32768];
  const int tid = threadIdx.x;
  const int wid = tid >> 6, lane = tid & 63;
  const int l15 = lane & 15, l4 = lane >> 4;
  const int wm = wid >> 2, wn = wid & 3;
  // XCD remap: 384 blocks, 48/XCD; consecutive wg share A-panel.
  const int wg = (blockIdx.x & 7) * ((int)gridDim.x >> 3) + (blockIdx.x >> 3);
  const int nx = 24;  // N/256
  const int bx = wg % nx, by = wg / nx;
  const int m0 = by << 8, n0 = bx << 8;
  const char* Ab = (const char*)A;
  const char* Bb = (const char*)Bm;
  const size_t rs = (size_t)K * 2;

  const int sw = (l15 & 7) << 4;
  int aoff[4][2], boff[4][2];
  #pragma unroll
  for (int mm = 0; mm < 4; ++mm)
    #pragma unroll
    for (int ks = 0; ks < 2; ++ks)
      aoff[mm][ks] = (wm * 128 + mm * 16 + l15) * 128 + ((ks * 64 + 16 * l4) ^ sw);
  #pragma unroll
  for (int nn = 0; nn < 4; ++nn)
    #pragma unroll
    for (int ks = 0; ks < 2; ++ks)
      boff[nn][ks] = (wn * 64 + nn * 16 + l15) * 128 + ((ks * 64 + 16 * l4) ^ sw);

  f32x4 acc[8][4];
  #pragma unroll
  for (int i = 0; i < 8; ++i)
    #pragma unroll
    for (int jx = 0; jx < 4; ++jx) acc[i][jx] = (f32x4){0.f, 0.f, 0.f, 0.f};
  bf16x8 areg[4][2], breg[4][2];

  auto STG = [&](const char* srcB, char* dstHalf) {
    #pragma unroll
    for (int jj = 0; jj < 2; ++jj) {
      int o = jj * 8192 + tid * 16;
      int row = o >> 7, cb = o & 127;
      gload_lds16(srcB + (size_t)row * rs + (cb ^ ((row & 7) << 4)), dstHalf + jj * 8192 + wid * 1024);
    }
  };

  const int NKT = K >> 6, NIT = NKT >> 1;
  // prologue: B(t0)h0,h1, A(t0)h0,h1, B(t1)h0,h1, A(t1)h0  (7 half-tiles)
  STG(Bb + (size_t)n0 * rs, sB0);
  STG(Bb + (size_t)(n0 + 128) * rs, sB0 + 16384);
  STG(Ab + (size_t)m0 * rs, sA0);
  STG(Ab + (size_t)(m0 + 128) * rs, sA0 + 16384);
  STG(Bb + (size_t)n0 * rs + 128, sB1);
  STG(Bb + (size_t)(n0 + 128) * rs + 128, sB1 + 16384);
  STG(Ab + (size_t)m0 * rs + 128, sA1);
  asm volatile("s_waitcnt vmcnt(6)" ::: "memory");
  __builtin_amdgcn_sched_barrier(0);
  __builtin_amdgcn_s_barrier();

  for (int j = 0; j < NIT; ++j) {
    const size_t k1b = (size_t)(2 * j + 1) * 128;
    const size_t k2b = (size_t)(2 * j + 2) * 128;
    const size_t k3b = (size_t)(2 * j + 3) * 128;
    const bool g2 = (j + 1 < NIT);
    // p1: read buf0 A-lo + B-all; stage A(t1,buf1) h1
    rd_a8(areg, sA0, aoff, 0); rd_b8(breg, sB0, boff);
    STG(Ab + (size_t)(m0 + 128) * rs + k1b, sA1 + 16384);
    PH_PRE(); mfma_quad(acc, areg, breg, 0, 0); PH_POST();
    // p2: stage B(t2,buf0) h0
    if (g2) STG(Bb + (size_t)n0 * rs + k2b, sB0);
    PH_PRE(); mfma_quad(acc, areg, breg, 0, 2); PH_POST();
    // p3: read buf0 A-hi; stage B(t2,buf0) h1
    rd_a8(areg, sA0, aoff, 8192);
    if (g2) STG(Bb + (size_t)(n0 + 128) * rs + k2b, sB0 + 16384);
    PH_PRE(); mfma_quad(acc, areg, breg, 4, 0); PH_POST();
    // p4: stage A(t2,buf0) h0; WAIT1
    if (g2) STG(Ab + (size_t)m0 * rs + k2b, sA0);
    __builtin_amdgcn_s_barrier();
    asm volatile("s_waitcnt lgkmcnt(0)" ::: "memory");
    __builtin_amdgcn_sched_barrier(0);
    __builtin_amdgcn_s_setprio(1);
    mfma_quad(acc, areg, breg, 4, 2);
    __builtin_amdgcn_s_setprio(0);
    if (g2) { asm volatile("s_waitcnt vmcnt(6)" ::: "memory"); }
    else    { asm volatile("s_waitcnt vmcnt(0)" ::: "memory"); }
    __builtin_amdgcn_sched_barrier(0);
    __builtin_amdgcn_s_barrier();
    // p5: read buf1 A-lo + B-all; stage A(t2,buf0) h1
    rd_a8(areg, sA1, aoff, 0); rd_b8(breg, sB1, boff);
    if (g2) STG(Ab + (size_t)(m0 + 128) * rs + k2b, sA0 + 16384);
    PH_PRE(); mfma_quad(acc, areg, breg, 0, 0); PH_POST();
    // p6: stage B(t3,buf1) h0
    if (g2) STG(Bb + (size_t)n0 * rs + k3b, sB1);
    PH_PRE(); mfma_quad(acc, areg, breg, 0, 2); PH_POST();
    // p7: read buf1 A-hi; stage B(t3,buf1) h1
    rd_a8(areg, sA1, aoff, 8192);
    if (g2) STG(Bb + (size_t)(n0 + 128) * rs + k3b, sB1 + 16384);
    PH_PRE(); mfma_quad(acc, areg, breg, 4, 0); PH_POST();
    // p8: stage A(t3,buf1) h0; WAIT2
    if (g2) STG(Ab + (size_t)m0 * rs + k3b, sA1);
    __builtin_amdgcn_s_barrier();
    asm volatile("s_waitcnt lgkmcnt(0)" ::: "memory");
    __builtin_amdgcn_sched_barrier(0);
    __builtin_amdgcn_s_setprio(1);
    mfma_quad(acc, areg, breg, 4, 2);
    __builtin_amdgcn_s_setprio(0);
    if (g2) { asm volatile("s_waitcnt vmcnt(6)" ::: "memory"); __builtin_amdgcn_sched_barrier(0); }
    __builtin_amdgcn_s_barrier();
  }

  // epilogue: scatter to Q/K/V [B][H][L][D] bf16
  #pragma unroll
  for (int mi = 0; mi < 8; ++mi) {
    #pragma unroll
    for (int ni = 0; ni < 4; ++ni) {
      #pragma unroll
      for (int jj = 0; jj < 4; ++jj) {
        int gm = m0 + wm * 128 + mi * 16 + l4 * 4 + jj;
        int gn = n0 + wn * 64 + ni * 16 + l15;
        int b = gm >> 11, l = gm & 2047;
        int which = gn >> 11, hid = gn & 2047;
        int h = hid >> 7, d = hid & 127;
        u16* dst = (which == 0) ? Qr : ((which == 1) ? Kr : Vr);
        dst[((size_t)(b * NH + h) * SEQ + l) * DH + d] = f2bf(acc[mi][ni][jj]);
      }
    }
  }
}

// ---------------- GEMM C = A * B^T (m97-style, used for out-proj) ----------------
template<int EPI>
__global__ __launch_bounds__(256)
void k_gemm(const u16* __restrict__ A, const u16* __restrict__ Bm,
            float* __restrict__ Cf, u16* __restrict__ Qr, u16* __restrict__ Kr, u16* __restrict__ Vr,
            int N, int K) {
  __shared__ alignas(16) char sA[128 * 128];
  __shared__ alignas(16) char sB[128 * 128];
  const int tid = threadIdx.x;
  const int wid = tid >> 6, lane = tid & 63;
  const int l15 = lane & 15, l4 = lane >> 4;
  const int m0 = blockIdx.y * 128, n0 = blockIdx.x * 128;
  const int wr = (wid >> 1) * 64, wc = (wid & 1) * 64;

  f32x4 acc[4][4];
  #pragma unroll
  for (int i = 0; i < 4; ++i)
    #pragma unroll
    for (int j = 0; j < 4; ++j)
      acc[i][j] = (f32x4){0.f, 0.f, 0.f, 0.f};

  const int nkt = K >> 6;
  for (int kt = 0; kt < nkt; ++kt) {
    const int k0 = kt << 6;
    __syncthreads();
    #pragma unroll
    for (int it = 0; it < 4; ++it) {
      int o = it * 4096 + tid * 16;
      int row = o >> 7, cb = o & 127;
      int scb = cb ^ ((row & 7) << 4);
      gload_lds16((const char*)A + ((size_t)(m0 + row) * K + k0) * 2 + scb, &sA[it * 4096 + wid * 1024]);
    }
    #pragma unroll
    for (int it = 0; it < 4; ++it) {
      int o = it * 4096 + tid * 16;
      int row = o >> 7, cb = o & 127;
      int scb = cb ^ ((row & 7) << 4);
      gload_lds16((const char*)Bm + ((size_t)(n0 + row) * K + k0) * 2 + scb, &sB[it * 4096 + wid * 1024]);
    }
    __syncthreads();
    #pragma unroll
    for (int kk = 0; kk < 2; ++kk) {
      bf16x8 av[4], bv[4];
      #pragma unroll
      for (int mi = 0; mi < 4; ++mi) {
        int row = wr + mi * 16 + l15;
        int colb = kk * 64 + 16 * l4;
        av[mi] = *(const bf16x8*)&sA[row * 128 + (colb ^ ((row & 7) << 4))];
      }
      #pragma unroll
      for (int ni = 0; ni < 4; ++ni) {
        int row = wc + ni * 16 + l15;
        int colb = kk * 64 + 16 * l4;
        bv[ni] = *(const bf16x8*)&sB[row * 128 + (colb ^ ((row & 7) << 4))];
      }
      #pragma unroll
      for (int mi = 0; mi < 4; ++mi)
        #pragma unroll
        for (int ni = 0; ni < 4; ++ni)
          acc[mi][ni] = __builtin_amdgcn_mfma_f32_16x16x32_bf16(av[mi], bv[ni], acc[mi][ni], 0, 0, 0);
    }
  }

  #pragma unroll
  for (int mi = 0; mi < 4; ++mi) {
    #pragma unroll
    for (int ni = 0; ni < 4; ++ni) {
      #pragma unroll
      for (int j = 0; j < 4; ++j) {
        int gm = m0 + wr + mi * 16 + l4 * 4 + j;
        int gn = n0 + wc + ni * 16 + l15;
        float v = acc[mi][ni][j];
        if (EPI == 0) {
          int b = gm >> 11, l = gm & 2047;
          int which = gn >> 11, hid = gn & 2047;
          int h = hid >> 7, d = hid & 127;
          u16* dst = (which == 0) ? Qr : ((which == 1) ? Kr : Vr);
          size_t idx = ((size_t)(b * NH + h) * SEQ + l) * DH + d;
          dst[idx] = f2bf(v);
        } else {
          Cf[(size_t)gm * N + gn] = v;
        }
      }
    }
  }
}

// ---------------- V transpose: Vr[bh][l][d] -> Vt[bh][d][l] ----------------
__global__ __launch_bounds__(256) void k_vtr(const u16* __restrict__ Vr, u16* __restrict__ Vt) {
  __shared__ u16 tile[64][72];
  const int k0 = blockIdx.x * 64, d0 = blockIdx.y * 64, bh = blockIdx.z;
  const u16* src = Vr + ((size_t)bh << 18);
  u16* dst = Vt + ((size_t)bh << 18);
  const int tid = threadIdx.x;
  #pragma unroll
  for (int it = 0; it < 2; ++it) {
    int e = it * 2048 + tid * 8;
    int r = e >> 6, c = e & 63;
    bf16x8 v = *(const bf16x8*)(src + (size_t)(k0 + r) * DH + d0 + c);
    *(bf16x8*)&tile[r][c] = v;
  }
  __syncthreads();
  #pragma unroll
  for (int it = 0; it < 2; ++it) {
    int e = it * 2048 + tid * 8;
    int rd = e >> 6, ck = e & 63;
    bf16x8 w;
    #pragma unroll
    for (int i = 0; i < 8; ++i) w[i] = (short)tile[ck + i][rd];
    *(bf16x8*)(dst + (size_t)(d0 + rd) * SEQ + k0 + ck) = w;
  }
}

// ---------------- RMSNorm + interleaved RoPE, in place on [B*H*L][128] bf16 ----------------
__global__ __launch_bounds__(256) void k_nrope(u16* __restrict__ T) {
  const int r = blockIdx.x * 4 + (threadIdx.x >> 6);
  const int lane = threadIdx.x & 63;
  u16* p = T + ((size_t)r << 7) + lane * 2;
  u32 pr = *(const u32*)p;
  float xe = bf2f((u16)(pr & 0xffffu));
  float xo = bf2f((u16)(pr >> 16));
  float ss = xe * xe + xo * xo;
  #pragma unroll
  for (int off = 1; off < 64; off <<= 1) ss += __shfl_xor(ss, off);
  float rinv = rsqrtf(ss * (1.f / 128.f) + 1e-5f);
  float e = xe * rinv, o = xo * rinv;
  int pos = r & (SEQ - 1);
  float freq = exp2f(-0.20762050593046014f * (float)lane);
  float ang = (float)pos * freq;
  float sn, cs;
  sincosf(ang, &sn, &cs);
  u32 outw = (u32)f2bf(o * cs - e * sn) | ((u32)f2bf(o * sn + e * cs) << 16);
  *(u32*)p = outw;
}

// ---------------- causal flash attention, paired q-tiles, double-buffered ----------------
#define PSTR 68   // u16 elements per P row (136 B)

__device__ __forceinline__ void attn_tile(const char* sK, const char* sVt, char* sPw,
                                          const bf16x8* aq, f32x4* accO, float* m_, float* se,
                                          int q0, int kb, bool diag, int l15, int l4) {
  const float scale = 0.08838834764831845f;  // 1/sqrt(128)
  f32x4 sacc[4];
  __builtin_amdgcn_s_setprio(1);
  #pragma unroll
  for (int sj = 0; sj < 4; ++sj) {
    sacc[sj] = (f32x4){0.f, 0.f, 0.f, 0.f};
    int row = sj * 16 + l15;
    #pragma unroll
    for (int kk = 0; kk < 4; ++kk) {
      int colb = kk * 64 + 16 * l4;
      bf16x8 bk = *(const bf16x8*)&sK[(row << 8) + (colb ^ ((row & 7) << 4))];
      sacc[sj] = __builtin_amdgcn_mfma_f32_16x16x32_bf16(aq[kk], bk, sacc[sj], 0, 0, 0);
    }
  }
  __builtin_amdgcn_s_setprio(0);
  float pvv[4][4], rm[4], rs[4], corr[4];
  #pragma unroll
  for (int j = 0; j < 4; ++j) {
    int qpos = q0 + l4 * 4 + j;
    float mx = -1e30f;
    #pragma unroll
    for (int sj = 0; sj < 4; ++sj) {
      float s = sacc[sj][j] * scale;
      if (diag) {
        int kpos = kb + sj * 16 + l15;
        s = (kpos > qpos) ? -1e30f : s;
      }
      pvv[sj][j] = s;
      mx = fmaxf(mx, s);
    }
    rm[j] = mx;
  }
  #pragma unroll
  for (int off = 1; off < 16; off <<= 1) {
    #pragma unroll
    for (int j = 0; j < 4; ++j) rm[j] = fmaxf(rm[j], __shfl_xor(rm[j], off));
  }
  #pragma unroll
  for (int j = 0; j < 4; ++j) {
    float mn = fmaxf(m_[j], rm[j]);
    corr[j] = __expf(m_[j] - mn);
    m_[j] = mn;
    float sum = 0.f;
    #pragma unroll
    for (int sj = 0; sj < 4; ++sj) { float pe = __expf(pvv[sj][j] - mn); pvv[sj][j] = pe; sum += pe; }
    rs[j] = sum;
  }
  #pragma unroll
  for (int off = 1; off < 16; off <<= 1) {
    #pragma unroll
    for (int j = 0; j < 4; ++j) rs[j] += __shfl_xor(rs[j], off);
  }
  #pragma unroll
  for (int j = 0; j < 4; ++j) se[j] = se[j] * corr[j] + rs[j];
  #pragma unroll
  for (int db = 0; db < 8; ++db) {
    f32x4 a = accO[db];
    #pragma unroll
    for (int j = 0; j < 4; ++j) a[j] *= corr[j];
    accO[db] = a;
  }
  {
    u16* Pw = (u16*)sPw;
    #pragma unroll
    for (int sj = 0; sj < 4; ++sj)
      #pragma unroll
      for (int j = 0; j < 4; ++j)
        Pw[(l4 * 4 + j) * PSTR + sj * 16 + l15] = f2bf(pvv[sj][j]);
  }
  bf16x8 pa0 = *(const bf16x8*)(sPw + l15 * (PSTR * 2) + 16 * l4);
  bf16x8 pa1 = *(const bf16x8*)(sPw + l15 * (PSTR * 2) + 16 * l4 + 64);
  __builtin_amdgcn_s_setprio(1);
  #pragma unroll
  for (int db = 0; db < 8; ++db) {
    int row = db * 16 + l15;
    const char* vb = &sVt[row * 128];
    bf16x8 b0 = *(const bf16x8*)&vb[(16 * l4) ^ ((row & 7) << 4)];
    bf16x8 b1 = *(const bf16x8*)&vb[(64 + 16 * l4) ^ ((row & 7) << 4)];
    accO[db] = __builtin_amdgcn_mfma_f32_16x16x32_bf16(pa0, b0, accO[db], 0, 0, 0);
    accO[db] = __builtin_amdgcn_mfma_f32_16x16x32_bf16(pa1, b1, accO[db], 0, 0, 0);
  }
  __builtin_amdgcn_s_setprio(0);
}

__device__ __forceinline__ void stage_kv(const char* Kp, const char* Vtp, int kb,
                                         char* bK, char* bV, int tid, int wid) {
  #pragma unroll
  for (int it = 0; it < 4; ++it) {
    int o = it * 4096 + tid * 16;
    int row = o >> 8, cb = o & 255;
    int scb = cb ^ ((row & 7) << 4);
    gload_lds16(Kp + (size_t)(kb + row) * 256 + scb, &bK[it * 4096 + wid * 1024]);
  }
  #pragma unroll
  for (int it = 0; it < 4; ++it) {
    int o = it * 4096 + tid * 16;
    int row = o >> 7, cb = o & 127;
    int scb = cb ^ ((row & 7) << 4);
    gload_lds16(Vtp + (size_t)row * (SEQ * 2) + kb * 2 + scb, &bV[it * 4096 + wid * 1024]);
  }
}

// grid: 512 blocks (1-D, XCD-remapped); block 256 = 4 waves. Pair p: q-tiles p and 31-p.
__global__ __launch_bounds__(256, 2)
void k_attn(const u16* __restrict__ Q, const u16* __restrict__ Kg,
            const u16* __restrict__ Vt, u16* __restrict__ O) {
  __shared__ alignas(16) char sK0[64 * 256];
  __shared__ alignas(16) char sK1[64 * 256];
  __shared__ alignas(16) char sV0[128 * 128];
  __shared__ alignas(16) char sV1[128 * 128];
  __shared__ alignas(16) char sP[4 * 16 * PSTR * 2];
  const int tid = threadIdx.x, wid = tid >> 6, lane = tid & 63;
  const int l15 = lane & 15, l4 = lane >> 4;
  const int i = blockIdx.x;
  const int xcd = i & 7, slot = i >> 3;
  const int p = slot & 15;
  const int bh = xcd + 8 * (slot >> 4);
  const int b = bh >> 4, h = bh & 15;
  const int tA = p, tB = 31 - p;
  const u16* Qp = Q + ((size_t)bh << 18);
  const char* Kp = (const char*)(Kg + ((size_t)bh << 18));
  const char* Vtp = (const char*)(Vt + ((size_t)bh << 18));
  const int q0A = tA * 64 + wid * 16;
  const int q0B = tB * 64 + wid * 16;

  bf16x8 aqA[4], aqB[4];
  #pragma unroll
  for (int kk = 0; kk < 4; ++kk) {
    aqA[kk] = *(const bf16x8*)(Qp + (size_t)(q0A + l15) * DH + kk * 32 + 8 * l4);
    aqB[kk] = *(const bf16x8*)(Qp + (size_t)(q0B + l15) * DH + kk * 32 + 8 * l4);
  }

  f32x4 accA[8], accB[8];
  #pragma unroll
  for (int i2 = 0; i2 < 8; ++i2) { accA[i2] = (f32x4){0.f,0.f,0.f,0.f}; accB[i2] = (f32x4){0.f,0.f,0.f,0.f}; }
  float mA[4] = {-1e30f,-1e30f,-1e30f,-1e30f}, mB[4] = {-1e30f,-1e30f,-1e30f,-1e30f};
  float seA[4] = {0.f,0.f,0.f,0.f}, seB[4] = {0.f,0.f,0.f,0.f};

  char* sPw = sP + wid * (16 * PSTR * 2);
  const int nt = tB + 1;

  stage_kv(Kp, Vtp, 0, sK0, sV0, tid, wid);
  for (int t = 0; t < nt; ++t) {
    char* bK = (t & 1) ? sK1 : sK0;
    char* bV = (t & 1) ? sV1 : sV0;
    if (t + 1 < nt) {
      stage_kv(Kp, Vtp, (t + 1) << 6, (t & 1) ? sK0 : sK1, (t & 1) ? sV0 : sV1, tid, wid);
      asm volatile("s_waitcnt vmcnt(8)" ::: "memory");
    } else {
      asm volatile("s_waitcnt vmcnt(0)" ::: "memory");
    }
    __builtin_amdgcn_sched_barrier(0);
    __builtin_amdgcn_s_barrier();

    const int kb = t << 6;
    attn_tile(bK, bV, sPw, aqB, accB, mB, seB, q0B, kb, t == tB, l15, l4);
    if (t <= tA)
      attn_tile(bK, bV, sPw, aqA, accA, mA, seA, q0A, kb, t == tA, l15, l4);

    __builtin_amdgcn_s_barrier();
  }

  #pragma unroll
  for (int db = 0; db < 8; ++db) {
    #pragma unroll
    for (int j = 0; j < 4; ++j) {
      int d = db * 16 + l15;
      int qA = q0A + l4 * 4 + j;
      int qB = q0B + l4 * 4 + j;
      O[(size_t)(b * SEQ + qA) * HID + h * DH + d] = f2bf(accA[db][j] / seA[j]);
      O[(size_t)(b * SEQ + qB) * HID + h * DH + d] = f2bf(accB[db][j] / seB[j]);
    }
  }
}

extern "C" void kernel_launch(void* const* d_in, const int* in_sizes, int n_in,
                              void* d_out, int out_size, void* d_ws, size_t ws_size,
                              hipStream_t stream) {
  (void)in_sizes; (void)n_in; (void)out_size; (void)ws_size;
  const float* x = (const float*)d_in[0];
  const float* Wqkv = (const float*)d_in[1];
  const float* Wout = (const float*)d_in[2];
  float* out = (float*)d_out;
  char* ws = (char*)d_ws;

  u16* xb  = (u16*)(ws);                                   // 16 MB [4096][2048] bf16 (also attn O)
  u16* wqb = (u16*)(ws + (size_t)16777216);                // 24 MB [6144][2048] bf16
  u16* Vt  = wqb;                                          // aliases wqb AFTER gemm0 (16 MB)
  u16* wob = (u16*)(ws + (size_t)16777216 + 25165824);     // 8 MB  [2048][2048] bf16
  u16* Qr  = (u16*)(ws + (size_t)50331648);                // 16 MB each (8388608 u16 elements)
  u16* Kr  = Qr + (size_t)8388608;
  u16* Vr  = Kr + (size_t)8388608;
  u16* Ob  = xb;

  k_cvt<<<dim3(1024), dim3(256), 0, stream>>>(x, xb, (NB * SEQ * HID) / 4);
  k_cvt<<<dim3(1024), dim3(256), 0, stream>>>(Wqkv, wqb, (3 * HID * HID) / 4);
  k_cvt<<<dim3(1024), dim3(256), 0, stream>>>(Wout, wob, (HID * HID) / 4);

  k_gemm8<<<dim3(384), dim3(512), 0, stream>>>(xb, wqb, Qr, Kr, Vr, HID);

  k_vtr<<<dim3(SEQ / 64, DH / 64, NB * NH), dim3(256), 0, stream>>>(Vr, Vt);
  k_nrope<<<dim3((NB * NH * SEQ) / 4), dim3(256), 0, stream>>>(Qr);
  k_nrope<<<dim3((NB * NH * SEQ) / 4), dim3(256), 0, stream>>>(Kr);

  k_attn<<<dim3(512), dim3(256), 0, stream>>>(Qr, Kr, Vt, Ob);

  k_gemm<1><<<dim3(16, 32), dim3(256), 0, stream>>>(Ob, wob, out, nullptr, nullptr, nullptr, HID, HID);
}

// Round 6
// 301.794 us; speedup vs baseline: 1.0882x; 1.0882x over previous
//
#include <hip/hip_runtime.h>
#include <stdint.h>
#include <math.h>

typedef unsigned short u16;
typedef unsigned int u32;
typedef __attribute__((ext_vector_type(8))) short bf16x8;
typedef __attribute__((ext_vector_type(4))) float f32x4;

#define SEQ 2048
#define HID 2048
#define NH  16
#define DH  128
#define NB  2

typedef __attribute__((address_space(1))) const u32 gu32;
typedef __attribute__((address_space(3))) u32 lu32;

__device__ __forceinline__ u16 f2bf(float f) {
  u32 u = __float_as_uint(f);
  return (u16)((u + 0x7fffu + ((u >> 16) & 1u)) >> 16);
}
__device__ __forceinline__ float bf2f(u16 h) { return __uint_as_float(((u32)h) << 16); }

__device__ __forceinline__ void gload_lds16(const void* g, void* l) {
  __builtin_amdgcn_global_load_lds((gu32*)g, (lu32*)l, 16, 0, 0);
}

// ---------------- fp32 -> bf16 convert ----------------
__global__ __launch_bounds__(256) void k_cvt(const float* __restrict__ src, u16* __restrict__ dst, int n4) {
  int i = blockIdx.x * 256 + threadIdx.x;
  int stride = gridDim.x * 256;
  for (; i < n4; i += stride) {
    float4 v = ((const float4*)src)[i];
    ushort4 o;
    o.x = f2bf(v.x); o.y = f2bf(v.y); o.z = f2bf(v.z); o.w = f2bf(v.w);
    ((ushort4*)dst)[i] = o;
  }
}

// ---------------- GEMM C = A * B^T  (A:[M,K], B:[N,K], bf16 in, fp32 acc) ----------------
// 1-D grid with bijective XCD chunk remap (grid % 8 == 0).
template<int EPI>
__global__ __launch_bounds__(256)
void k_gemm(const u16* __restrict__ A, const u16* __restrict__ Bm,
            float* __restrict__ Cf, u16* __restrict__ Qr, u16* __restrict__ Kr, u16* __restrict__ Vr,
            int N, int K, int NX) {
  __shared__ alignas(16) char sA[128 * 128];
  __shared__ alignas(16) char sB[128 * 128];
  const int tid = threadIdx.x;
  const int wid = tid >> 6, lane = tid & 63;
  const int l15 = lane & 15, l4 = lane >> 4;
  const int nwg = gridDim.x, bid = blockIdx.x;
  const int wg = (bid & 7) * (nwg >> 3) + (bid >> 3);
  const int bx = wg % NX, by = wg / NX;
  const int m0 = by * 128, n0 = bx * 128;
  const int wr = (wid >> 1) * 64, wc = (wid & 1) * 64;

  f32x4 acc[4][4];
  #pragma unroll
  for (int i = 0; i < 4; ++i)
    #pragma unroll
    for (int j = 0; j < 4; ++j)
      acc[i][j] = (f32x4){0.f, 0.f, 0.f, 0.f};

  const int nkt = K >> 6;
  for (int kt = 0; kt < nkt; ++kt) {
    const int k0 = kt << 6;
    __syncthreads();
    #pragma unroll
    for (int it = 0; it < 4; ++it) {
      int o = it * 4096 + tid * 16;
      int row = o >> 7, cb = o & 127;
      int scb = cb ^ ((row & 7) << 4);
      gload_lds16((const char*)A + ((size_t)(m0 + row) * K + k0) * 2 + scb, &sA[it * 4096 + wid * 1024]);
    }
    #pragma unroll
    for (int it = 0; it < 4; ++it) {
      int o = it * 4096 + tid * 16;
      int row = o >> 7, cb = o & 127;
      int scb = cb ^ ((row & 7) << 4);
      gload_lds16((const char*)Bm + ((size_t)(n0 + row) * K + k0) * 2 + scb, &sB[it * 4096 + wid * 1024]);
    }
    __syncthreads();
    #pragma unroll
    for (int kk = 0; kk < 2; ++kk) {
      bf16x8 av[4], bv[4];
      #pragma unroll
      for (int mi = 0; mi < 4; ++mi) {
        int row = wr + mi * 16 + l15;
        int colb = kk * 64 + 16 * l4;
        av[mi] = *(const bf16x8*)&sA[row * 128 + (colb ^ ((row & 7) << 4))];
      }
      #pragma unroll
      for (int ni = 0; ni < 4; ++ni) {
        int row = wc + ni * 16 + l15;
        int colb = kk * 64 + 16 * l4;
        bv[ni] = *(const bf16x8*)&sB[row * 128 + (colb ^ ((row & 7) << 4))];
      }
      #pragma unroll
      for (int mi = 0; mi < 4; ++mi)
        #pragma unroll
        for (int ni = 0; ni < 4; ++ni)
          acc[mi][ni] = __builtin_amdgcn_mfma_f32_16x16x32_bf16(av[mi], bv[ni], acc[mi][ni], 0, 0, 0);
    }
  }

  #pragma unroll
  for (int mi = 0; mi < 4; ++mi) {
    #pragma unroll
    for (int ni = 0; ni < 4; ++ni) {
      #pragma unroll
      for (int j = 0; j < 4; ++j) {
        int gm = m0 + wr + mi * 16 + l4 * 4 + j;
        int gn = n0 + wc + ni * 16 + l15;
        float v = acc[mi][ni][j];
        if (EPI == 0) {
          int b = gm >> 11, l = gm & 2047;
          int which = gn >> 11, hid = gn & 2047;
          int h = hid >> 7, d = hid & 127;
          u16* dst = (which == 0) ? Qr : ((which == 1) ? Kr : Vr);
          size_t idx = ((size_t)(b * NH + h) * SEQ + l) * DH + d;
          dst[idx] = f2bf(v);
        } else {
          Cf[(size_t)gm * N + gn] = v;
        }
      }
    }
  }
}

// ---------------- V transpose: Vr[bh][l][d] -> Vt[bh][d][l] ----------------
__global__ __launch_bounds__(256) void k_vtr(const u16* __restrict__ Vr, u16* __restrict__ Vt) {
  __shared__ u16 tile[64][72];
  const int k0 = blockIdx.x * 64, d0 = blockIdx.y * 64, bh = blockIdx.z;
  const u16* src = Vr + ((size_t)bh << 18);
  u16* dst = Vt + ((size_t)bh << 18);
  const int tid = threadIdx.x;
  #pragma unroll
  for (int it = 0; it < 2; ++it) {
    int e = it * 2048 + tid * 8;
    int r = e >> 6, c = e & 63;
    bf16x8 v = *(const bf16x8*)(src + (size_t)(k0 + r) * DH + d0 + c);
    *(bf16x8*)&tile[r][c] = v;
  }
  __syncthreads();
  #pragma unroll
  for (int it = 0; it < 2; ++it) {
    int e = it * 2048 + tid * 8;
    int rd = e >> 6, ck = e & 63;
    bf16x8 w;
    #pragma unroll
    for (int i = 0; i < 8; ++i) w[i] = (short)tile[ck + i][rd];
    *(bf16x8*)(dst + (size_t)(d0 + rd) * SEQ + k0 + ck) = w;
  }
}

// ---------------- RMSNorm + interleaved RoPE (+ optional scale), in place ----------------
__global__ __launch_bounds__(256) void k_nrope(u16* __restrict__ T, float mul) {
  const int r = blockIdx.x * 4 + (threadIdx.x >> 6);
  const int lane = threadIdx.x & 63;
  u16* p = T + ((size_t)r << 7) + lane * 2;
  u32 pr = *(const u32*)p;
  float xe = bf2f((u16)(pr & 0xffffu));
  float xo = bf2f((u16)(pr >> 16));
  float ss = xe * xe + xo * xo;
  #pragma unroll
  for (int off = 1; off < 64; off <<= 1) ss += __shfl_xor(ss, off);
  float rinv = rsqrtf(ss * (1.f / 128.f) + 1e-5f);
  float e = xe * rinv, o = xo * rinv;
  int pos = r & (SEQ - 1);
  float freq = exp2f(-0.20762050593046014f * (float)lane);
  float ang = (float)pos * freq;
  float sn, cs;
  sincosf(ang, &sn, &cs);
  u32 outw = (u32)f2bf((o * cs - e * sn) * mul) | ((u32)f2bf((o * sn + e * cs) * mul) << 16);
  *(u32*)p = outw;
}

// ---------------- causal flash attention, swapped-QK^T lane-local softmax ----------------
#define PSTR 72   // u16 elements per P row (144 B, 16B-aligned b128 reads)

__device__ __forceinline__ void attn_tile(const char* sK, const char* sVt, char* sPw,
                                          const bf16x8* aq, f32x4* accO, float& m_, float& se,
                                          int qpos, int kb, bool diag, int l15, int l4) {
  // S^T = K * Q : lane holds S[q = l15-row][k' = kb + sj*16 + l4*4 + j]
  f32x4 sacc[4];
  __builtin_amdgcn_s_setprio(1);
  #pragma unroll
  for (int sj = 0; sj < 4; ++sj) {
    sacc[sj] = (f32x4){0.f, 0.f, 0.f, 0.f};
    int row = sj * 16 + l15;
    #pragma unroll
    for (int kk = 0; kk < 4; ++kk) {
      int colb = kk * 64 + 16 * l4;
      bf16x8 bk = *(const bf16x8*)&sK[(row << 8) + (colb ^ ((row & 7) << 4))];
      sacc[sj] = __builtin_amdgcn_mfma_f32_16x16x32_bf16(bk, aq[kk], sacc[sj], 0, 0, 0);
    }
  }
  __builtin_amdgcn_s_setprio(0);
  float pvv[16];
  float mx = -1e30f;
  #pragma unroll
  for (int sj = 0; sj < 4; ++sj)
    #pragma unroll
    for (int j = 0; j < 4; ++j) {
      float s = sacc[sj][j];
      if (diag) {
        int kpos = kb + sj * 16 + l4 * 4 + j;
        s = (kpos > qpos) ? -1e30f : s;
      }
      pvv[sj * 4 + j] = s;
      mx = fmaxf(mx, s);
    }
  mx = fmaxf(mx, __shfl_xor(mx, 16));
  mx = fmaxf(mx, __shfl_xor(mx, 32));
  float mn = fmaxf(m_, mx);
  float corr = __expf(m_ - mn);
  m_ = mn;
  float sum = 0.f;
  #pragma unroll
  for (int i = 0; i < 16; ++i) { float pe = __expf(pvv[i] - mn); pvv[i] = pe; sum += pe; }
  sum += __shfl_xor(sum, 16);
  sum += __shfl_xor(sum, 32);
  se = se * corr + sum;
  // broadcast corr from softmax-lane (q = l15) to accumulator rows (q = l4*4+j)
  float corr4[4];
  #pragma unroll
  for (int j = 0; j < 4; ++j) corr4[j] = __shfl(corr, l4 * 4 + j);
  #pragma unroll
  for (int db = 0; db < 8; ++db) {
    f32x4 a = accO[db];
    #pragma unroll
    for (int j = 0; j < 4; ++j) a[j] *= corr4[j];
    accO[db] = a;
  }
  // P -> LDS, packed u32 (2 bf16 per store): row = q (l15), col = k'
  u16* Pw = (u16*)sPw;
  #pragma unroll
  for (int sj = 0; sj < 4; ++sj)
    #pragma unroll
    for (int jp = 0; jp < 2; ++jp) {
      u32 w = (u32)f2bf(pvv[sj * 4 + jp * 2]) | ((u32)f2bf(pvv[sj * 4 + jp * 2 + 1]) << 16);
      *(u32*)&Pw[l15 * PSTR + sj * 16 + l4 * 4 + jp * 2] = w;
    }
  bf16x8 pa0 = *(const bf16x8*)(sPw + l15 * (PSTR * 2) + 16 * l4);
  bf16x8 pa1 = *(const bf16x8*)(sPw + l15 * (PSTR * 2) + 16 * l4 + 64);
  __builtin_amdgcn_s_setprio(1);
  #pragma unroll
  for (int db = 0; db < 8; ++db) {
    int row = db * 16 + l15;
    const char* vb = &sVt[row * 128];
    bf16x8 b0 = *(const bf16x8*)&vb[(16 * l4) ^ ((row & 7) << 4)];
    bf16x8 b1 = *(const bf16x8*)&vb[(64 + 16 * l4) ^ ((row & 7) << 4)];
    accO[db] = __builtin_amdgcn_mfma_f32_16x16x32_bf16(pa0, b0, accO[db], 0, 0, 0);
    accO[db] = __builtin_amdgcn_mfma_f32_16x16x32_bf16(pa1, b1, accO[db], 0, 0, 0);
  }
  __builtin_amdgcn_s_setprio(0);
}

__device__ __forceinline__ void stage_kv(const char* Kp, const char* Vtp, int kb,
                                         char* bK, char* bV, int tid, int wid) {
  #pragma unroll
  for (int it = 0; it < 4; ++it) {
    int o = it * 4096 + tid * 16;
    int row = o >> 8, cb = o & 255;
    int scb = cb ^ ((row & 7) << 4);
    gload_lds16(Kp + (size_t)(kb + row) * 256 + scb, &bK[it * 4096 + wid * 1024]);
  }
  #pragma unroll
  for (int it = 0; it < 4; ++it) {
    int o = it * 4096 + tid * 16;
    int row = o >> 7, cb = o & 127;
    int scb = cb ^ ((row & 7) << 4);
    gload_lds16(Vtp + (size_t)row * (SEQ * 2) + kb * 2 + scb, &bV[it * 4096 + wid * 1024]);
  }
}

// grid: 512 blocks (1-D, XCD-remapped); block 256 = 4 waves. Pair p: q-tiles p and 31-p.
__global__ __launch_bounds__(256, 2)
void k_attn(const u16* __restrict__ Q, const u16* __restrict__ Kg,
            const u16* __restrict__ Vt, u16* __restrict__ O) {
  __shared__ alignas(16) char sK0[64 * 256];
  __shared__ alignas(16) char sK1[64 * 256];
  __shared__ alignas(16) char sV0[128 * 128];
  __shared__ alignas(16) char sV1[128 * 128];
  __shared__ alignas(16) char sP[4 * 16 * PSTR * 2];
  const int tid = threadIdx.x, wid = tid >> 6, lane = tid & 63;
  const int l15 = lane & 15, l4 = lane >> 4;
  const int i = blockIdx.x;
  const int xcd = i & 7, slot = i >> 3;
  const int p = slot & 15;
  const int bh = xcd + 8 * (slot >> 4);
  const int b = bh >> 4, h = bh & 15;
  const int tA = p, tB = 31 - p;
  const u16* Qp = Q + ((size_t)bh << 18);
  const char* Kp = (const char*)(Kg + ((size_t)bh << 18));
  const char* Vtp = (const char*)(Vt + ((size_t)bh << 18));
  const int q0A = tA * 64 + wid * 16;
  const int q0B = tB * 64 + wid * 16;

  bf16x8 aqA[4], aqB[4];
  #pragma unroll
  for (int kk = 0; kk < 4; ++kk) {
    aqA[kk] = *(const bf16x8*)(Qp + (size_t)(q0A + l15) * DH + kk * 32 + 8 * l4);
    aqB[kk] = *(const bf16x8*)(Qp + (size_t)(q0B + l15) * DH + kk * 32 + 8 * l4);
  }

  f32x4 accA[8], accB[8];
  #pragma unroll
  for (int i2 = 0; i2 < 8; ++i2) { accA[i2] = (f32x4){0.f,0.f,0.f,0.f}; accB[i2] = (f32x4){0.f,0.f,0.f,0.f}; }
  float mA = -1e30f, mB = -1e30f, seA = 0.f, seB = 0.f;

  char* sPw = sP + wid * (16 * PSTR * 2);
  const int nt = tB + 1;

  stage_kv(Kp, Vtp, 0, sK0, sV0, tid, wid);
  for (int t = 0; t < nt; ++t) {
    char* bK = (t & 1) ? sK1 : sK0;
    char* bV = (t & 1) ? sV1 : sV0;
    if (t + 1 < nt) {
      stage_kv(Kp, Vtp, (t + 1) << 6, (t & 1) ? sK0 : sK1, (t & 1) ? sV0 : sV1, tid, wid);
      asm volatile("s_waitcnt vmcnt(8)" ::: "memory");
    } else {
      asm volatile("s_waitcnt vmcnt(0)" ::: "memory");
    }
    __builtin_amdgcn_sched_barrier(0);
    __builtin_amdgcn_s_barrier();

    const int kb = t << 6;
    attn_tile(bK, bV, sPw, aqB, accB, mB, seB, q0B + l15, kb, t == tB, l15, l4);
    if (t <= tA)
      attn_tile(bK, bV, sPw, aqA, accA, mA, seA, q0A + l15, kb, t == tA, l15, l4);

    __builtin_amdgcn_s_barrier();
  }

  float seA4[4], seB4[4];
  #pragma unroll
  for (int j = 0; j < 4; ++j) {
    seA4[j] = __shfl(seA, l4 * 4 + j);
    seB4[j] = __shfl(seB, l4 * 4 + j);
  }
  #pragma unroll
  for (int db = 0; db < 8; ++db) {
    #pragma unroll
    for (int j = 0; j < 4; ++j) {
      int d = db * 16 + l15;
      int qA = q0A + l4 * 4 + j;
      int qB = q0B + l4 * 4 + j;
      O[(size_t)(b * SEQ + qA) * HID + h * DH + d] = f2bf(accA[db][j] / seA4[j]);
      O[(size_t)(b * SEQ + qB) * HID + h * DH + d] = f2bf(accB[db][j] / seB4[j]);
    }
  }
}

extern "C" void kernel_launch(void* const* d_in, const int* in_sizes, int n_in,
                              void* d_out, int out_size, void* d_ws, size_t ws_size,
                              hipStream_t stream) {
  (void)in_sizes; (void)n_in; (void)out_size; (void)ws_size;
  const float* x = (const float*)d_in[0];
  const float* Wqkv = (const float*)d_in[1];
  const float* Wout = (const float*)d_in[2];
  float* out = (float*)d_out;
  char* ws = (char*)d_ws;

  u16* xb  = (u16*)(ws);                                   // 16 MB [4096][2048] bf16 (also attn O)
  u16* wqb = (u16*)(ws + (size_t)16777216);                // 24 MB [6144][2048] bf16
  u16* Vt  = wqb;                                          // aliases wqb AFTER gemm0 (16 MB)
  u16* wob = (u16*)(ws + (size_t)16777216 + 25165824);     // 8 MB  [2048][2048] bf16
  u16* Qr  = (u16*)(ws + (size_t)50331648);                // 16 MB each (8388608 u16 elements)
  u16* Kr  = Qr + (size_t)8388608;
  u16* Vr  = Kr + (size_t)8388608;
  u16* Ob  = xb;

  k_cvt<<<dim3(1024), dim3(256), 0, stream>>>(x, xb, (NB * SEQ * HID) / 4);
  k_cvt<<<dim3(1024), dim3(256), 0, stream>>>(Wqkv, wqb, (3 * HID * HID) / 4);
  k_cvt<<<dim3(1024), dim3(256), 0, stream>>>(Wout, wob, (HID * HID) / 4);

  k_gemm<0><<<dim3(1536), dim3(256), 0, stream>>>(xb, wqb, nullptr, Qr, Kr, Vr, 3 * HID, HID, 48);

  k_vtr<<<dim3(SEQ / 64, DH / 64, NB * NH), dim3(256), 0, stream>>>(Vr, Vt);
  k_nrope<<<dim3((NB * NH * SEQ) / 4), dim3(256), 0, stream>>>(Qr, 0.08838834764831845f);
  k_nrope<<<dim3((NB * NH * SEQ) / 4), dim3(256), 0, stream>>>(Kr, 1.0f);

  k_attn<<<dim3(512), dim3(256), 0, stream>>>(Qr, Kr, Vt, Ob);

  k_gemm<1><<<dim3(512), dim3(256), 0, stream>>>(Ob, wob, out, nullptr, nullptr, nullptr, HID, HID, 16);
}

// Round 7
// 297.730 us; speedup vs baseline: 1.1031x; 1.0137x over previous
//
#include <hip/hip_runtime.h>
#include <stdint.h>
#include <math.h>

typedef unsigned short u16;
typedef unsigned int u32;
typedef __attribute__((ext_vector_type(8))) short bf16x8;
typedef __attribute__((ext_vector_type(4))) float f32x4;

#define SEQ 2048
#define HID 2048
#define NH  16
#define DH  128
#define NB  2

typedef __attribute__((address_space(1))) const u32 gu32;
typedef __attribute__((address_space(3))) u32 lu32;

__device__ __forceinline__ u16 f2bf(float f) {
  u32 u = __float_as_uint(f);
  return (u16)((u + 0x7fffu + ((u >> 16) & 1u)) >> 16);
}
__device__ __forceinline__ float bf2f(u16 h) { return __uint_as_float(((u32)h) << 16); }

__device__ __forceinline__ void gload_lds16(const void* g, void* l) {
  __builtin_amdgcn_global_load_lds((gu32*)g, (lu32*)l, 16, 0, 0);
}

// ---------------- fused fp32 -> bf16 convert (3 regions, 1 launch) ----------------
__global__ __launch_bounds__(256) void k_cvt3(const float* __restrict__ s0, u16* __restrict__ d0, int n0,
                                              const float* __restrict__ s1, u16* __restrict__ d1, int n1,
                                              const float* __restrict__ s2, u16* __restrict__ d2, int n2) {
  int i = blockIdx.x * 256 + threadIdx.x;
  int stride = gridDim.x * 256;
  int total = n0 + n1 + n2;
  for (; i < total; i += stride) {
    const float* s; u16* d; int k = i;
    if (k < n0) { s = s0; d = d0; }
    else if (k < n0 + n1) { s = s1; d = d1; k -= n0; }
    else { s = s2; d = d2; k -= n0 + n1; }
    float4 v = ((const float4*)s)[k];
    ushort4 o;
    o.x = f2bf(v.x); o.y = f2bf(v.y); o.z = f2bf(v.z); o.w = f2bf(v.w);
    ((ushort4*)d)[k] = o;
  }
}

// ---------------- GEMM C = A * B^T  (A:[M,K], B:[N,K], bf16 in, fp32 acc) ----------------
// 1-D grid with XCD chunk remap (grid % 8 == 0).
template<int EPI>
__global__ __launch_bounds__(256)
void k_gemm(const u16* __restrict__ A, const u16* __restrict__ Bm,
            float* __restrict__ Cf, u16* __restrict__ Qr, u16* __restrict__ Kr, u16* __restrict__ Vr,
            int N, int K, int NX) {
  __shared__ alignas(16) char sA[128 * 128];
  __shared__ alignas(16) char sB[128 * 128];
  const int tid = threadIdx.x;
  const int wid = tid >> 6, lane = tid & 63;
  const int l15 = lane & 15, l4 = lane >> 4;
  const int nwg = gridDim.x, bid = blockIdx.x;
  const int wg = (bid & 7) * (nwg >> 3) + (bid >> 3);
  const int bx = wg % NX, by = wg / NX;
  const int m0 = by * 128, n0 = bx * 128;
  const int wr = (wid >> 1) * 64, wc = (wid & 1) * 64;

  f32x4 acc[4][4];
  #pragma unroll
  for (int i = 0; i < 4; ++i)
    #pragma unroll
    for (int j = 0; j < 4; ++j)
      acc[i][j] = (f32x4){0.f, 0.f, 0.f, 0.f};

  const int nkt = K >> 6;
  for (int kt = 0; kt < nkt; ++kt) {
    const int k0 = kt << 6;
    __syncthreads();
    #pragma unroll
    for (int it = 0; it < 4; ++it) {
      int o = it * 4096 + tid * 16;
      int row = o >> 7, cb = o & 127;
      int scb = cb ^ ((row & 7) << 4);
      gload_lds16((const char*)A + ((size_t)(m0 + row) * K + k0) * 2 + scb, &sA[it * 4096 + wid * 1024]);
    }
    #pragma unroll
    for (int it = 0; it < 4; ++it) {
      int o = it * 4096 + tid * 16;
      int row = o >> 7, cb = o & 127;
      int scb = cb ^ ((row & 7) << 4);
      gload_lds16((const char*)Bm + ((size_t)(n0 + row) * K + k0) * 2 + scb, &sB[it * 4096 + wid * 1024]);
    }
    __syncthreads();
    #pragma unroll
    for (int kk = 0; kk < 2; ++kk) {
      bf16x8 av[4], bv[4];
      #pragma unroll
      for (int mi = 0; mi < 4; ++mi) {
        int row = wr + mi * 16 + l15;
        int colb = kk * 64 + 16 * l4;
        av[mi] = *(const bf16x8*)&sA[row * 128 + (colb ^ ((row & 7) << 4))];
      }
      #pragma unroll
      for (int ni = 0; ni < 4; ++ni) {
        int row = wc + ni * 16 + l15;
        int colb = kk * 64 + 16 * l4;
        bv[ni] = *(const bf16x8*)&sB[row * 128 + (colb ^ ((row & 7) << 4))];
      }
      #pragma unroll
      for (int mi = 0; mi < 4; ++mi)
        #pragma unroll
        for (int ni = 0; ni < 4; ++ni)
          acc[mi][ni] = __builtin_amdgcn_mfma_f32_16x16x32_bf16(av[mi], bv[ni], acc[mi][ni], 0, 0, 0);
    }
  }

  #pragma unroll
  for (int mi = 0; mi < 4; ++mi) {
    #pragma unroll
    for (int ni = 0; ni < 4; ++ni) {
      #pragma unroll
      for (int j = 0; j < 4; ++j) {
        int gm = m0 + wr + mi * 16 + l4 * 4 + j;
        int gn = n0 + wc + ni * 16 + l15;
        float v = acc[mi][ni][j];
        if (EPI == 0) {
          int b = gm >> 11, l = gm & 2047;
          int which = gn >> 11, hid = gn & 2047;
          int h = hid >> 7, d = hid & 127;
          u16* dst = (which == 0) ? Qr : ((which == 1) ? Kr : Vr);
          size_t idx = ((size_t)(b * NH + h) * SEQ + l) * DH + d;
          dst[idx] = f2bf(v);
        } else {
          Cf[(size_t)gm * N + gn] = v;
        }
      }
    }
  }
}

// ---------------- V transpose: Vr[bh][l][d] -> Vt[bh][d][l] ----------------
__global__ __launch_bounds__(256) void k_vtr(const u16* __restrict__ Vr, u16* __restrict__ Vt) {
  __shared__ u16 tile[64][72];
  const int k0 = blockIdx.x * 64, d0 = blockIdx.y * 64, bh = blockIdx.z;
  const u16* src = Vr + ((size_t)bh << 18);
  u16* dst = Vt + ((size_t)bh << 18);
  const int tid = threadIdx.x;
  #pragma unroll
  for (int it = 0; it < 2; ++it) {
    int e = it * 2048 + tid * 8;
    int r = e >> 6, c = e & 63;
    bf16x8 v = *(const bf16x8*)(src + (size_t)(k0 + r) * DH + d0 + c);
    *(bf16x8*)&tile[r][c] = v;
  }
  __syncthreads();
  #pragma unroll
  for (int it = 0; it < 2; ++it) {
    int e = it * 2048 + tid * 8;
    int rd = e >> 6, ck = e & 63;
    bf16x8 w;
    #pragma unroll
    for (int i = 0; i < 8; ++i) w[i] = (short)tile[ck + i][rd];
    *(bf16x8*)(dst + (size_t)(d0 + rd) * SEQ + k0 + ck) = w;
  }
}

// -------- RMSNorm + interleaved RoPE, in place; blockIdx.y: 0 -> Q (mul=mq), 1 -> K --------
__global__ __launch_bounds__(256) void k_nrope2(u16* __restrict__ Qr, u16* __restrict__ Kr, float mq) {
  u16* T = blockIdx.y ? Kr : Qr;
  const float mul = blockIdx.y ? 1.0f : mq;
  const int r = blockIdx.x * 4 + (threadIdx.x >> 6);
  const int lane = threadIdx.x & 63;
  u16* p = T + ((size_t)r << 7) + lane * 2;
  u32 pr = *(const u32*)p;
  float xe = bf2f((u16)(pr & 0xffffu));
  float xo = bf2f((u16)(pr >> 16));
  float ss = xe * xe + xo * xo;
  #pragma unroll
  for (int off = 1; off < 64; off <<= 1) ss += __shfl_xor(ss, off);
  float rinv = rsqrtf(ss * (1.f / 128.f) + 1e-5f);
  float e = xe * rinv, o = xo * rinv;
  int pos = r & (SEQ - 1);
  float freq = exp2f(-0.20762050593046014f * (float)lane);
  float ang = (float)pos * freq;
  float sn, cs;
  sincosf(ang, &sn, &cs);
  u32 outw = (u32)f2bf((o * cs - e * sn) * mul) | ((u32)f2bf((o * sn + e * cs) * mul) << 16);
  *(u32*)p = outw;
}

// ---------------- causal flash attention ----------------
// Swapped QK^T (lane-local softmax rows), exp2 domain (scale*log2e folded into Q),
// defer-max rescale, dual-tile interleave with shared K/V register operands.

__device__ __forceinline__ void smax(f32x4 (&sacc)[4], float& m_, float& se,
                                     f32x4* accO, u32 (&pw)[8],
                                     bool diag, int qpos, int kb, int l15, int l4) {
  if (diag) {
    #pragma unroll
    for (int sj = 0; sj < 4; ++sj)
      #pragma unroll
      for (int j = 0; j < 4; ++j) {
        int kpos = kb + sj * 16 + l4 * 4 + j;
        if (kpos > qpos) sacc[sj][j] = -1e30f;
      }
  }
  float mx = sacc[0][0];
  #pragma unroll
  for (int sj = 0; sj < 4; ++sj)
    #pragma unroll
    for (int j = 0; j < 4; ++j) mx = fmaxf(mx, sacc[sj][j]);
  mx = fmaxf(mx, __shfl_xor(mx, 16));
  mx = fmaxf(mx, __shfl_xor(mx, 32));
  if (!__all(mx <= m_ + 8.f)) {
    float mn = fmaxf(m_, mx);
    float corr = __builtin_exp2f(m_ - mn);
    m_ = mn;
    se *= corr;
    float corr4[4];
    #pragma unroll
    for (int j = 0; j < 4; ++j) corr4[j] = __shfl(corr, l4 * 4 + j);
    #pragma unroll
    for (int db = 0; db < 8; ++db) {
      f32x4 a = accO[db];
      #pragma unroll
      for (int j = 0; j < 4; ++j) a[j] *= corr4[j];
      accO[db] = a;
    }
  }
  float sum = 0.f;
  #pragma unroll
  for (int sj = 0; sj < 4; ++sj)
    #pragma unroll
    for (int jp = 0; jp < 2; ++jp) {
      float p0 = __builtin_exp2f(sacc[sj][jp * 2]     - m_);
      float p1 = __builtin_exp2f(sacc[sj][jp * 2 + 1] - m_);
      pw[sj * 2 + jp] = (u32)f2bf(p0) | ((u32)f2bf(p1) << 16);
      sum += p0 + p1;
    }
  sum += __shfl_xor(sum, 16);
  sum += __shfl_xor(sum, 32);
  se += sum;
}

__device__ __forceinline__ void pwrite(char* sPw, const u32 (&pw)[8], int l15, int l4) {
  const int sw = (l15 & 7) << 4;
  char* base = sPw + l15 * 128;
  #pragma unroll
  for (int sj = 0; sj < 4; ++sj)
    #pragma unroll
    for (int jp = 0; jp < 2; ++jp)
      *(u32*)(base + ((sj * 32 + l4 * 8 + jp * 4) ^ sw)) = pw[sj * 2 + jp];
}

__device__ __forceinline__ void stage_kv(const char* Kp, const char* Vtp, int kb,
                                         char* bK, char* bV, int tid, int wid) {
  #pragma unroll
  for (int it = 0; it < 4; ++it) {
    int o = it * 4096 + tid * 16;
    int row = o >> 8, cb = o & 255;
    int scb = cb ^ ((row & 7) << 4);
    gload_lds16(Kp + (size_t)(kb + row) * 256 + scb, &bK[it * 4096 + wid * 1024]);
  }
  #pragma unroll
  for (int it = 0; it < 4; ++it) {
    int o = it * 4096 + tid * 16;
    int row = o >> 7, cb = o & 127;
    int scb = cb ^ ((row & 7) << 4);
    gload_lds16(Vtp + (size_t)row * (SEQ * 2) + kb * 2 + scb, &bV[it * 4096 + wid * 1024]);
  }
}

// grid: 512 blocks (XCD-remapped); block 256 = 4 waves. Pair p: q-tiles p and 31-p.
__global__ __launch_bounds__(256, 2)
void k_attn(const u16* __restrict__ Q, const u16* __restrict__ Kg,
            const u16* __restrict__ Vt, u16* __restrict__ O) {
  __shared__ alignas(16) char sK0[64 * 256];
  __shared__ alignas(16) char sK1[64 * 256];
  __shared__ alignas(16) char sV0[128 * 128];
  __shared__ alignas(16) char sV1[128 * 128];
  __shared__ alignas(16) char sP[4 * 2048];
  const int tid = threadIdx.x, wid = tid >> 6, lane = tid & 63;
  const int l15 = lane & 15, l4 = lane >> 4;
  const int i = blockIdx.x;
  const int xcd = i & 7, slot = i >> 3;
  const int p = slot & 15;
  const int bh = xcd + 8 * (slot >> 4);
  const int b = bh >> 4, h = bh & 15;
  const int tA = p, tB = 31 - p;
  const u16* Qp = Q + ((size_t)bh << 18);
  const char* Kp = (const char*)(Kg + ((size_t)bh << 18));
  const char* Vtp = (const char*)(Vt + ((size_t)bh << 18));
  const int q0A = tA * 64 + wid * 16;
  const int q0B = tB * 64 + wid * 16;

  bf16x8 aqA[4], aqB[4];
  #pragma unroll
  for (int kk = 0; kk < 4; ++kk) {
    aqA[kk] = *(const bf16x8*)(Qp + (size_t)(q0A + l15) * DH + kk * 32 + 8 * l4);
    aqB[kk] = *(const bf16x8*)(Qp + (size_t)(q0B + l15) * DH + kk * 32 + 8 * l4);
  }

  f32x4 accA[8], accB[8];
  #pragma unroll
  for (int i2 = 0; i2 < 8; ++i2) { accA[i2] = (f32x4){0.f,0.f,0.f,0.f}; accB[i2] = (f32x4){0.f,0.f,0.f,0.f}; }
  float mA = -1e30f, mB = -1e30f, seA = 0.f, seB = 0.f;

  char* sPw = sP + wid * 2048;
  const int psw = (l15 & 7) << 4;
  const int nt = tB + 1;

  stage_kv(Kp, Vtp, 0, sK0, sV0, tid, wid);
  for (int t = 0; t < nt; ++t) {
    char* bK = (t & 1) ? sK1 : sK0;
    char* bV = (t & 1) ? sV1 : sV0;
    if (t + 1 < nt) {
      stage_kv(Kp, Vtp, (t + 1) << 6, (t & 1) ? sK0 : sK1, (t & 1) ? sV0 : sV1, tid, wid);
      asm volatile("s_waitcnt vmcnt(8)" ::: "memory");
    } else {
      asm volatile("s_waitcnt vmcnt(0)" ::: "memory");
    }
    __builtin_amdgcn_sched_barrier(0);
    __builtin_amdgcn_s_barrier();

    const int kb = t << 6;
    if (t <= tA) {
      // ---- dual path: both sub-tiles, shared K/V operands, interleaved softmax ----
      f32x4 sb[4], sa[4];
      __builtin_amdgcn_s_setprio(1);
      #pragma unroll
      for (int sj = 0; sj < 4; ++sj) {
        sb[sj] = (f32x4){0.f,0.f,0.f,0.f};
        sa[sj] = (f32x4){0.f,0.f,0.f,0.f};
        int row = sj * 16 + l15;
        const char* rK = bK + (row << 8);
        int swr = (row & 7) << 4;
        #pragma unroll
        for (int kk = 0; kk < 4; ++kk) {
          bf16x8 bkv = *(const bf16x8*)(rK + ((kk * 64 + 16 * l4) ^ swr));
          sb[sj] = __builtin_amdgcn_mfma_f32_16x16x32_bf16(bkv, aqB[kk], sb[sj], 0, 0, 0);
          sa[sj] = __builtin_amdgcn_mfma_f32_16x16x32_bf16(bkv, aqA[kk], sa[sj], 0, 0, 0);
        }
      }
      __builtin_amdgcn_s_setprio(0);
      u32 pwB[8], pwA[8];
      smax(sb, mB, seB, accB, pwB, false, 0, kb, l15, l4);
      smax(sa, mA, seA, accA, pwA, t == tA, q0A + l15, kb, l15, l4);
      pwrite(sPw, pwB, l15, l4);
      bf16x8 paB0 = *(const bf16x8*)(sPw + l15 * 128 + ((16 * l4) ^ psw));
      bf16x8 paB1 = *(const bf16x8*)(sPw + l15 * 128 + ((64 + 16 * l4) ^ psw));
      pwrite(sPw, pwA, l15, l4);
      bf16x8 paA0 = *(const bf16x8*)(sPw + l15 * 128 + ((16 * l4) ^ psw));
      bf16x8 paA1 = *(const bf16x8*)(sPw + l15 * 128 + ((64 + 16 * l4) ^ psw));
      __builtin_amdgcn_s_setprio(1);
      #pragma unroll
      for (int db = 0; db < 8; ++db) {
        int row = db * 16 + l15;
        const char* vb = bV + row * 128;
        int swr = (row & 7) << 4;
        bf16x8 b0 = *(const bf16x8*)(vb + ((16 * l4) ^ swr));
        bf16x8 b1 = *(const bf16x8*)(vb + ((64 + 16 * l4) ^ swr));
        accB[db] = __builtin_amdgcn_mfma_f32_16x16x32_bf16(paB0, b0, accB[db], 0, 0, 0);
        accA[db] = __builtin_amdgcn_mfma_f32_16x16x32_bf16(paA0, b0, accA[db], 0, 0, 0);
        accB[db] = __builtin_amdgcn_mfma_f32_16x16x32_bf16(paB1, b1, accB[db], 0, 0, 0);
        accA[db] = __builtin_amdgcn_mfma_f32_16x16x32_bf16(paA1, b1, accA[db], 0, 0, 0);
      }
      __builtin_amdgcn_s_setprio(0);
    } else {
      // ---- single path: B only ----
      f32x4 sb[4];
      __builtin_amdgcn_s_setprio(1);
      #pragma unroll
      for (int sj = 0; sj < 4; ++sj) {
        sb[sj] = (f32x4){0.f,0.f,0.f,0.f};
        int row = sj * 16 + l15;
        const char* rK = bK + (row << 8);
        int swr = (row & 7) << 4;
        #pragma unroll
        for (int kk = 0; kk < 4; ++kk) {
          bf16x8 bkv = *(const bf16x8*)(rK + ((kk * 64 + 16 * l4) ^ swr));
          sb[sj] = __builtin_amdgcn_mfma_f32_16x16x32_bf16(bkv, aqB[kk], sb[sj], 0, 0, 0);
        }
      }
      __builtin_amdgcn_s_setprio(0);
      u32 pwB[8];
      smax(sb, mB, seB, accB, pwB, t == tB, q0B + l15, kb, l15, l4);
      pwrite(sPw, pwB, l15, l4);
      bf16x8 paB0 = *(const bf16x8*)(sPw + l15 * 128 + ((16 * l4) ^ psw));
      bf16x8 paB1 = *(const bf16x8*)(sPw + l15 * 128 + ((64 + 16 * l4) ^ psw));
      __builtin_amdgcn_s_setprio(1);
      #pragma unroll
      for (int db = 0; db < 8; ++db) {
        int row = db * 16 + l15;
        const char* vb = bV + row * 128;
        int swr = (row & 7) << 4;
        bf16x8 b0 = *(const bf16x8*)(vb + ((16 * l4) ^ swr));
        bf16x8 b1 = *(const bf16x8*)(vb + ((64 + 16 * l4) ^ swr));
        accB[db] = __builtin_amdgcn_mfma_f32_16x16x32_bf16(paB0, b0, accB[db], 0, 0, 0);
        accB[db] = __builtin_amdgcn_mfma_f32_16x16x32_bf16(paB1, b1, accB[db], 0, 0, 0);
      }
      __builtin_amdgcn_s_setprio(0);
    }

    __builtin_amdgcn_s_barrier();
  }

  float seA4[4], seB4[4];
  #pragma unroll
  for (int j = 0; j < 4; ++j) {
    seA4[j] = __shfl(seA, l4 * 4 + j);
    seB4[j] = __shfl(seB, l4 * 4 + j);
  }
  #pragma unroll
  for (int db = 0; db < 8; ++db) {
    #pragma unroll
    for (int j = 0; j < 4; ++j) {
      int d = db * 16 + l15;
      int qA = q0A + l4 * 4 + j;
      int qB = q0B + l4 * 4 + j;
      O[(size_t)(b * SEQ + qA) * HID + h * DH + d] = f2bf(accA[db][j] / seA4[j]);
      O[(size_t)(b * SEQ + qB) * HID + h * DH + d] = f2bf(accB[db][j] / seB4[j]);
    }
  }
}

extern "C" void kernel_launch(void* const* d_in, const int* in_sizes, int n_in,
                              void* d_out, int out_size, void* d_ws, size_t ws_size,
                              hipStream_t stream) {
  (void)in_sizes; (void)n_in; (void)out_size; (void)ws_size;
  const float* x = (const float*)d_in[0];
  const float* Wqkv = (const float*)d_in[1];
  const float* Wout = (const float*)d_in[2];
  float* out = (float*)d_out;
  char* ws = (char*)d_ws;

  u16* xb  = (u16*)(ws);                                   // 16 MB [4096][2048] bf16 (also attn O)
  u16* wqb = (u16*)(ws + (size_t)16777216);                // 24 MB [6144][2048] bf16
  u16* Vt  = wqb;                                          // aliases wqb AFTER gemm0 (16 MB)
  u16* wob = (u16*)(ws + (size_t)16777216 + 25165824);     // 8 MB  [2048][2048] bf16
  u16* Qr  = (u16*)(ws + (size_t)50331648);                // 16 MB each (8388608 u16 elements)
  u16* Kr  = Qr + (size_t)8388608;
  u16* Vr  = Kr + (size_t)8388608;
  u16* Ob  = xb;

  // q pre-scale: (1/sqrt(128)) * log2(e)  -> softmax in exp2 domain
  const float mq = 0.08838834764831845f * 1.4426950408889634f;

  k_cvt3<<<dim3(2048), dim3(256), 0, stream>>>(x, xb, (NB * SEQ * HID) / 4,
                                               Wqkv, wqb, (3 * HID * HID) / 4,
                                               Wout, wob, (HID * HID) / 4);

  k_gemm<0><<<dim3(1536), dim3(256), 0, stream>>>(xb, wqb, nullptr, Qr, Kr, Vr, 3 * HID, HID, 48);

  k_vtr<<<dim3(SEQ / 64, DH / 64, NB * NH), dim3(256), 0, stream>>>(Vr, Vt);
  k_nrope2<<<dim3((NB * NH * SEQ) / 4, 2), dim3(256), 0, stream>>>(Qr, Kr, mq);

  k_attn<<<dim3(512), dim3(256), 0, stream>>>(Qr, Kr, Vt, Ob);

  k_gemm<1><<<dim3(512), dim3(256), 0, stream>>>(Ob, wob, out, nullptr, nullptr, nullptr, HID, HID, 16);
}